// Round 6
// baseline (242.185 us; speedup 1.0000x reference)
//
#include <hip/hip_runtime.h>

// Problem constants (from reference setup_inputs): B=2, H=W=128.
#define B_ITEMS 2
#define W_IMG   128
#define N_PTS   16384          // H*W
#define QS      2              // col-split across blocks
#define CH_GRID 2048           // max Utot = 4 s * 256 rowgroups * QS
#define BIGF    3.4e38f

// ---------------------------------------------------------------------------
// Kernel 1: compaction (R7 structure, proven). Also inits the rmG min table
// (65536 slots == 256 blocks x 256 threads) and zeroes out[0].
//   raw[pos] = (x, y, z, |q|^2)        row side
//   tf [pos] = (-2x, -2y, -2z, |q|^2)  col side: d = |p|^2 + fma3(p, tf)
// ---------------------------------------------------------------------------
__global__ __launch_bounds__(256) void prep_kernel(
        const float* __restrict__ pred,
        const float* __restrict__ gt,
        const int*   __restrict__ mask,
        const float* fxp, const float* fyp,
        const float* cxp, const float* cyp,
        int*    __restrict__ cnt,       // [0]=np0 [1]=np1 [2]=ng0 [3]=ng1
        float4* __restrict__ pR, float4* __restrict__ gR,   // raw   [B][N]
        float4* __restrict__ pT, float4* __restrict__ gT,   // transf[B][N]
        float*  __restrict__ rmG,       // [4][N_PTS] per-row min table
        float*  __restrict__ out) {
    int s    = blockIdx.x >> 6;
    int b    = s & 1;
    int isG  = s >> 1;
    int tid  = threadIdx.x;
    int idx  = (blockIdx.x & 63) * 256 + tid;
    int lane = tid & 63, w = tid >> 6;

    if (blockIdx.x == 0 && tid == 0) out[0] = 0.0f;
    rmG[(blockIdx.x << 8) + tid] = BIGF;

    float x, y, z;
    if (!isG) {
        float fx = *fxp, fy = *fyp, cx = *cxp, cy = *cyp;
        float u = (float)(idx & (W_IMG - 1));
        float v = (float)(idx >> 7);
        z = pred[b * N_PTS + idx];
        x = (u - cx) / fx * z;
        y = (v - cy) / fy * z;
    } else {
        x = gt[(b * 3 + 0) * N_PTS + idx];
        y = gt[(b * 3 + 1) * N_PTS + idx];
        z = gt[(b * 3 + 2) * N_PTS + idx];
    }
    int  mv = mask[b * N_PTS + idx];
    bool ok = (mv > 0) && (((x + y) + z) != 0.0f);

    unsigned long long bal = __ballot(ok);
    int nw  = __popcll(bal);
    int pre = __popcll(bal & ((1ull << lane) - 1ull));

    __shared__ int wbase[4];
    __shared__ int blockbase;
    if (lane == 0) wbase[w] = nw;
    __syncthreads();
    if (tid == 0) {
        int s0 = 0;
#pragma unroll
        for (int i = 0; i < 4; ++i) { int t = wbase[i]; wbase[i] = s0; s0 += t; }
        blockbase = s0 ? atomicAdd(&cnt[s], s0) : 0;
    }
    __syncthreads();

    if (ok) {
        int pos = blockbase + wbase[w] + pre;
        float ps = fmaf(z, z, fmaf(y, y, x * x));
        float4* __restrict__ raw = (isG ? gR : pR) + b * N_PTS;
        float4* __restrict__ tf  = (isG ? gT : pT) + b * N_PTS;
        raw[pos] = make_float4(x, y, z, ps);
        tf[pos]  = make_float4(-2.0f * x, -2.0f * y, -2.0f * z, ps);
    }
}

// ---------------------------------------------------------------------------
// Kernel 2 (R16): direct-global chamfer with NAMED-SCALAR row tile.
// R4/R5 lesson (PMC: VGPR=48-52 < 64-float live set, VALUBusy 15%):
// float[16] per-thread arrays exceed hipcc's promotion threshold -> scratch
// (rule #20); the asm pin can't rescue an unpromoted alloca. float[8]
// arrays promoted fine in R0/R1. Fix: 8 rows/thread as macro-generated
// NAMED SCALARS — no alloca exists, scratch impossible. Live set ~60 VGPR
// -> 8 blocks/CU resident (2048-block grid) = 8 waves/SIMD.
// Hot loop (unchanged concept from R5, proven correct): B cols read
// directly from global (B <=512 KB, L2-resident; wave reads a 128B
// segment, 8 lanes/address broadcast). Per 2 cols: 2 global_load_dwordx4
// + 56 VALU inst (1:28) — latency hidden by 8 waves/SIMD. No LDS staging,
// no hot-loop barriers.
//  - combine: 3 shfl_xor (tc fold) -> sm[w][row] -> ONE barrier -> 4-way
//    min -> atomicMin into rmG (int-order on nonneg floats; proven R1-R5).
//  - finish fused via done-counter (proven R2-R5): last block sums rmG.
// ---------------------------------------------------------------------------
__global__ __launch_bounds__(256, 4) void chamfer_kernel(
        const int*    __restrict__ cnt,
        const float4* __restrict__ pR, const float4* __restrict__ gR,
        const float4* __restrict__ pT, const float4* __restrict__ gT,
        float* __restrict__ rmG,
        int*   __restrict__ done,
        float* __restrict__ out) {
    int np0 = cnt[0], np1 = cnt[1], ng0 = cnt[2], ng1 = cnt[3];
    int naArr[4] = {np0, ng0, np1, ng1};
    int nbArr[4] = {ng0, np0, ng1, np1};
    const float4* Arow[4] = {pR, gR, pR + N_PTS, gR + N_PTS};
    const float4* Bcol[4] = {gT, pT, gT + N_PTS, pT + N_PTS};

    int units[4];
    int Utot = 0;
#pragma unroll
    for (int i = 0; i < 4; ++i) {
        units[i] = (naArr[i] > 0 && nbArr[i] > 0) ? (((naArr[i] + 63) >> 6) * QS) : 0;
        Utot += units[i];
    }

    int tid  = threadIdx.x;
    int lane = tid & 63;
    int w    = __builtin_amdgcn_readfirstlane(tid >> 6);   // wave id, SGPR

    __shared__ float sm[4][64];
    __shared__ float wsum[4];
    __shared__ int   lastFlag;

    int u = blockIdx.x;
    if (u < Utot) {
        int s = 0;
        while (u >= units[s]) { u -= units[s]; ++s; }
        int na = naArr[s], nb = nbArr[s];
        const float4* __restrict__ A  = Arow[s];
        const float4* __restrict__ Bp = Bcol[s];
        int q       = u & (QS - 1);
        int rowbase = (u >> 1) * 64;

        int Lq  = (nb + QS - 1) / QS;        // per-block col range
        int cb0 = q * Lq;
        int cc  = min(nb - cb0, Lq); if (cc < 0) cc = 0;
        int Lw  = (cc + 3) >> 2;             // per-wave col range
        int wb  = cb0 + w * Lw;
        int wc  = min(cc - w * Lw, Lw); if (wc < 0) wc = 0;

        int tc = lane & 7, tr = lane >> 3;

        // 8 rows/thread as NAMED SCALARS: row_a = rowbase + a*8 + tr.
        // (rows >= na read finite ws poison, gated at the atomicMin)
#define ROWS(OP) OP(0) OP(1) OP(2) OP(3) OP(4) OP(5) OP(6) OP(7)
#define DECLA(a) float px##a, py##a, pz##a, rm##a;
        ROWS(DECLA)
#undef DECLA
#define LOADA(a) { float4 v_ = A[rowbase + a * 8 + tr]; \
        px##a = v_.x; py##a = v_.y; pz##a = v_.z; rm##a = BIGF; }
        ROWS(LOADA)
#undef LOADA

        // thread handles cols {wb + 16*it + tc, wb + 16*it + 8 + tc}
        int nIt = (wc + 15) >> 4;            // uniform per wave; can be 0

#define LOADC(J, DST) { \
        int j_ = (J); \
        float4 v_ = Bp[min(wb + j_, N_PTS - 1)]; \
        bool ok_ = j_ < wc; \
        DST.x = ok_ ? v_.x : 0.0f; DST.y = ok_ ? v_.y : 0.0f; \
        DST.z = ok_ ? v_.z : 0.0f; DST.w = ok_ ? v_.w : BIGF; }

#define DOROW(a) { \
        float d0_ = fmaf(px##a, c0.x, fmaf(py##a, c0.y, fmaf(pz##a, c0.z, c0.w))); \
        float d1_ = fmaf(px##a, c1.x, fmaf(py##a, c1.y, fmaf(pz##a, c1.z, c1.w))); \
        rm##a = fminf(fminf(rm##a, d0_), d1_); }

#pragma unroll 2
        for (int it = 0; it < nIt; ++it) {
            float4 c0, c1;
            int j0 = it * 16 + tc;
            if ((it + 1) * 16 <= wc) {       // full group: uniform fast path
                c0 = Bp[wb + j0];
                c1 = Bp[wb + j0 + 8];
            } else {                         // ragged tail: sentinel cols
                LOADC(j0, c0)
                LOADC(j0 + 8, c1)
            }
            ROWS(DOROW)
        }
#undef DOROW
#undef LOADC

        // fold over tc (lane bits 0..2): lanes sharing (tr,a) share a row
#define FOLD(a) { \
        rm##a = fminf(rm##a, __shfl_xor(rm##a, 1, 64)); \
        rm##a = fminf(rm##a, __shfl_xor(rm##a, 2, 64)); \
        rm##a = fminf(rm##a, __shfl_xor(rm##a, 4, 64)); }
        ROWS(FOLD)
#undef FOLD
        if (tc == 0) {
#define STORE(a) sm[w][a * 8 + tr] = rm##a;
            ROWS(STORE)
#undef STORE
        }
#undef ROWS
        __syncthreads();                     // the ONE barrier (wave combine)
        if (tid < 64) {
            float m = fminf(fminf(sm[0][tid], sm[1][tid]),
                            fminf(sm[2][tid], sm[3][tid]));
            int r2 = rowbase + tid;
            if (r2 < na) {
                float psv = A[r2].w;         // |p|^2 (L1-hot reload)
                float vr  = fmaxf(m + psv, 0.0f);    // nonneg -> int order ok
                atomicMin((int*)&rmG[(s << 14) + r2], __float_as_int(vr));
            }
        }
    }

    // -------- done-counter: last block (of all CH_GRID) does the final sum.
    __syncthreads();                         // block-uniform path
    __threadfence();
    if (tid == 0) {
        int old = atomicAdd(done, 1);
        lastFlag = (old == (int)gridDim.x - 1) ? 1 : 0;
    }
    __syncthreads();

    if (lastFlag) {                          // block-uniform branch
        int* rmGi = (int*)rmG;
        float acc = 0.0f;
#pragma unroll 1
        for (int s2 = 0; s2 < 4; ++s2) {
            if (nbArr[s2] <= 0) continue;    // no partner side -> contributes 0
            int na2  = naArr[s2];
            int base = s2 << 14;
            for (int k = tid; k < na2; k += 256)   // compacted prefix only
                acc += __int_as_float(__hip_atomic_load(&rmGi[base + k],
                        __ATOMIC_RELAXED, __HIP_MEMORY_SCOPE_AGENT));
        }
#pragma unroll
        for (int off = 32; off > 0; off >>= 1)
            acc += __shfl_down(acc, off, 64);
        if (lane == 0) wsum[tid >> 6] = acc;
        __syncthreads();
        if (tid == 0)
            out[0] = (wsum[0] + wsum[1] + wsum[2] + wsum[3]) * (1.0f / B_ITEMS);
    }
}

extern "C" void kernel_launch(void* const* d_in, const int* in_sizes, int n_in,
                              void* d_out, int out_size, void* d_ws, size_t ws_size,
                              hipStream_t stream) {
    const float* pred = (const float*)d_in[0];
    const float* gt   = (const float*)d_in[1];
    const int*   mask = (const int*)  d_in[2];
    const float* fx   = (const float*)d_in[3];
    const float* fy   = (const float*)d_in[4];
    const float* cx   = (const float*)d_in[5];
    const float* cy   = (const float*)d_in[6];
    float* out = (float*)d_out;

    // ws: [0,256) cnt+done | pR 512K | gR 512K | pT 512K | gT 512K | rmG 256K
    char* ws = (char*)d_ws;
    size_t SEG = (size_t)B_ITEMS * N_PTS * 16;
    int*    cnt  = (int*)ws;
    int*    done = cnt + 4;
    float4* pR   = (float4*)(ws + 256);
    float4* gR   = (float4*)(ws + 256 + SEG);
    float4* pT   = (float4*)(ws + 256 + 2 * SEG);
    float4* gT   = (float4*)(ws + 256 + 3 * SEG);
    float*  rmG  = (float*) (ws + 256 + 4 * SEG);

    hipMemsetAsync(cnt, 0, 32, stream);      // cnt[0..3] + done

    prep_kernel<<<dim3(256), 256, 0, stream>>>(
        pred, gt, mask, fx, fy, cx, cy, cnt, pR, gR, pT, gT, rmG, out);

    chamfer_kernel<<<dim3(CH_GRID), 256, 0, stream>>>(
        cnt, pR, gR, pT, gT, rmG, done, out);
}

// Round 7
// 100.787 us; speedup vs baseline: 2.4029x; 2.4029x over previous
//
#include <hip/hip_runtime.h>

// Problem constants (from reference setup_inputs): B=2, H=W=128.
#define B_ITEMS 2
#define W_IMG   128
#define N_PTS   16384          // H*W
#define QS      2              // col-split across blocks
#define CH_GRID 2048           // max Utot = 4 s * 256 rowgroups * QS
#define BIGF    3.4e38f

// ---------------------------------------------------------------------------
// Kernel 1: compaction (R7 structure, proven). Also inits the rmG min table
// (65536 slots == 256 blocks x 256 threads) and zeroes out[0].
//   raw[pos] = (x, y, z, |q|^2)        row side
//   tf [pos] = (-2x, -2y, -2z, |q|^2)  col side: d = |p|^2 + fma3(p, tf)
// ---------------------------------------------------------------------------
__global__ __launch_bounds__(256) void prep_kernel(
        const float* __restrict__ pred,
        const float* __restrict__ gt,
        const int*   __restrict__ mask,
        const float* fxp, const float* fyp,
        const float* cxp, const float* cyp,
        int*    __restrict__ cnt,       // [0]=np0 [1]=np1 [2]=ng0 [3]=ng1
        float4* __restrict__ pR, float4* __restrict__ gR,   // raw   [B][N]
        float4* __restrict__ pT, float4* __restrict__ gT,   // transf[B][N]
        float*  __restrict__ rmG,       // [4][N_PTS] per-row min table
        float*  __restrict__ out) {
    int s    = blockIdx.x >> 6;
    int b    = s & 1;
    int isG  = s >> 1;
    int tid  = threadIdx.x;
    int idx  = (blockIdx.x & 63) * 256 + tid;
    int lane = tid & 63, w = tid >> 6;

    if (blockIdx.x == 0 && tid == 0) out[0] = 0.0f;
    rmG[(blockIdx.x << 8) + tid] = BIGF;

    float x, y, z;
    if (!isG) {
        float fx = *fxp, fy = *fyp, cx = *cxp, cy = *cyp;
        float u = (float)(idx & (W_IMG - 1));
        float v = (float)(idx >> 7);
        z = pred[b * N_PTS + idx];
        x = (u - cx) / fx * z;
        y = (v - cy) / fy * z;
    } else {
        x = gt[(b * 3 + 0) * N_PTS + idx];
        y = gt[(b * 3 + 1) * N_PTS + idx];
        z = gt[(b * 3 + 2) * N_PTS + idx];
    }
    int  mv = mask[b * N_PTS + idx];
    bool ok = (mv > 0) && (((x + y) + z) != 0.0f);

    unsigned long long bal = __ballot(ok);
    int nw  = __popcll(bal);
    int pre = __popcll(bal & ((1ull << lane) - 1ull));

    __shared__ int wbase[4];
    __shared__ int blockbase;
    if (lane == 0) wbase[w] = nw;
    __syncthreads();
    if (tid == 0) {
        int s0 = 0;
#pragma unroll
        for (int i = 0; i < 4; ++i) { int t = wbase[i]; wbase[i] = s0; s0 += t; }
        blockbase = s0 ? atomicAdd(&cnt[s], s0) : 0;
    }
    __syncthreads();

    if (ok) {
        int pos = blockbase + wbase[w] + pre;
        float ps = fmaf(z, z, fmaf(y, y, x * x));
        float4* __restrict__ raw = (isG ? gR : pR) + b * N_PTS;
        float4* __restrict__ tf  = (isG ? gT : pT) + b * N_PTS;
        raw[pos] = make_float4(x, y, z, ps);
        tf[pos]  = make_float4(-2.0f * x, -2.0f * y, -2.0f * z, ps);
    }
}

// ---------------------------------------------------------------------------
// Kernel 1b: sentinel-pad each compacted B-side (transformed) array up to a
// multiple of 1024 cols. Removes ALL ragged-tail masking from the chamfer
// hot loop (every tile is full, uniform trip counts, global_load_lds needs
// no masks). Sentinel (0,0,0,BIGF) never wins a min. 4 blocks x 1024 thr.
// ---------------------------------------------------------------------------
__global__ __launch_bounds__(1024) void pad_kernel(
        const int* __restrict__ cnt,
        float4* __restrict__ pT, float4* __restrict__ gT) {
    int s = blockIdx.x;                      // 0:pT b0  1:pT b1  2:gT b0  3:gT b1
    float4* arr = ((s >> 1) ? gT : pT) + (s & 1) * N_PTS;
    int n = cnt[s];
    int pos = n + threadIdx.x;
    if (pos < ((n + 1023) & ~1023))          // <= N_PTS always
        arr[pos] = make_float4(0.0f, 0.0f, 0.0f, BIGF);
}

// ---------------------------------------------------------------------------
// Kernel 2 (R17): block-staged chamfer (R0/R1 proven skeleton) with DEPTH-3
// pipelined staging via global_load_lds + counted vmcnt (T3/T4).
// R4-R6 lesson: three different shallow-pipelined structures all hit
// 172-180 us at 15% VALU — effective load-service latency under full-chip
// streaming is 1000s of cycles; only deep in-flight staging tolerates it.
// R0's dbuf (1 tile = ~1000 cy ahead) gave 35 us; this holds 3 tiles
// (~3000+ cy) in flight and never drains vmcnt to 0 in the main loop.
// Per tile t: VMCNT(4|2|0 counted) -> raw s_barrier -> sched_barrier(0)
//   -> issue stage(t+3) (2x global_load_lds w16/wave into ring slot) ->
//   compute tile t (16 ds_read_b128 + 8x16 min3-pairs per thread).
// Safety (hand-verified): consume needs own-vmcnt + barrier (each wave
// stages its own quarter, waits, joins) OK; overwrite of slot (t+3)&3
// [= tile t-1] is issued only after barrier(t), which all waves reach
// only after compute(t-1) OK. Tails eliminated by pad_kernel.
//  - geometry: unit = 64 rows x col-half (QS=2), 8 rows/thread (arrays of
//    8 promote fine - R0/R1 evidence), tc=tid&31 spans 32 cols, tr=tid>>5.
//  - ending: 5 shfl_xor fold -> smin -> atomicMin rmG (proven R1) ->
//    separate finish dispatch (proven R1).
// ---------------------------------------------------------------------------
#define VMCNT(n) asm volatile("s_waitcnt vmcnt(" #n ")" ::: "memory")

__device__ __forceinline__ void stage_tile(const float4* __restrict__ src,
                                           float4* lds_base, int w, int lane) {
    // wave w stages float4 indices [w*128, w*128+128) of the 512-slot tile
    const float4* s0 = src + w * 128 + lane;
    __builtin_amdgcn_global_load_lds(
        (const __attribute__((address_space(1))) void*)(s0),
        (__attribute__((address_space(3))) void*)(lds_base + w * 128), 16, 0, 0);
    __builtin_amdgcn_global_load_lds(
        (const __attribute__((address_space(1))) void*)(s0 + 64),
        (__attribute__((address_space(3))) void*)(lds_base + w * 128 + 64), 16, 0, 0);
}

__global__ __launch_bounds__(256, 4) void chamfer_kernel(
        const int*    __restrict__ cnt,
        const float4* __restrict__ pR, const float4* __restrict__ gR,
        const float4* __restrict__ pT, const float4* __restrict__ gT,
        float* __restrict__ rmG) {
    int np0 = cnt[0], np1 = cnt[1], ng0 = cnt[2], ng1 = cnt[3];
    int naArr[4] = {np0, ng0, np1, ng1};
    int nbArr[4] = {ng0, np0, ng1, np1};
    const float4* Arow[4] = {pR, gR, pR + N_PTS, gR + N_PTS};
    const float4* Bcol[4] = {gT, pT, gT + N_PTS, pT + N_PTS};

    int units[4];
    int Utot = 0;
#pragma unroll
    for (int i = 0; i < 4; ++i) {
        units[i] = (naArr[i] > 0 && nbArr[i] > 0) ? (((naArr[i] + 63) >> 6) * QS) : 0;
        Utot += units[i];
    }

    int u = blockIdx.x;
    if (u >= Utot) return;
    int s = 0;
    while (u >= units[s]) { u -= units[s]; ++s; }
    int na = naArr[s], nb = nbArr[s];
    const float4* __restrict__ A  = Arow[s];
    const float4* __restrict__ Bp = Bcol[s];
    int q       = u & (QS - 1);
    int rowbase = (u >> 1) * 64;

    int nbPad  = (nb + 1023) & ~1023;        // pad_kernel guarantees data
    int Lq     = nbPad >> 1;                 // half length, mult of 512
    int cb0    = q * Lq;
    int ntiles = Lq >> 9;                    // >= 1 (nb > 0 by gating)

    int tid  = threadIdx.x;
    int lane = tid & 63;
    int w    = tid >> 6;
    int tc   = tid & 31, tr = tid >> 5;

    // 8 rows/thread: row = rowbase + a*8 + tr (rows >= na read finite ws
    // poison, gated at the atomicMin).
    float px[8], py[8], pz[8], rm[8];
#pragma unroll
    for (int a = 0; a < 8; ++a) {
        float4 v = A[rowbase + a * 8 + tr];
        px[a] = v.x; py[a] = v.y; pz[a] = v.z;
        rm[a] = BIGF;
    }

    __shared__ float4 sB[4][512];            // 4-slot ring (32 KB)
    __shared__ float  smin[64];

    const float4* __restrict__ Bq = Bp + cb0;

    // prologue: issue stages for tiles 0..2
    if (0 < ntiles) stage_tile(Bq, sB[0], w, lane);
    if (1 < ntiles) stage_tile(Bq + 512, sB[1], w, lane);
    if (2 < ntiles) stage_tile(Bq + 1024, sB[2], w, lane);

#pragma unroll 1
    for (int t = 0; t < ntiles; ++t) {
        int rem = ntiles - 1 - t;            // stages issued beyond t (<=2)
        if (rem >= 2)      { VMCNT(4); }     // keep t+1,t+2 in flight
        else if (rem == 1) { VMCNT(2); }
        else               { VMCNT(0); }
        __builtin_amdgcn_s_barrier();        // raw: no compiler vmcnt(0) drain
        __builtin_amdgcn_sched_barrier(0);   // nothing crosses the barrier
        if (t + 3 < ntiles)
            stage_tile(Bq + (t + 3) * 512, sB[(t + 3) & 3], w, lane);
        const float4* bufc = &sB[t & 3][tc];
#pragma unroll
        for (int cb = 0; cb < 16; cb += 2) {
            float4 c0 = bufc[cb * 32];       // b128, 2-way alias: free
            float4 c1 = bufc[cb * 32 + 32];
#pragma unroll
            for (int a = 0; a < 8; ++a) {
                float d0 = fmaf(px[a], c0.x,
                             fmaf(py[a], c0.y, fmaf(pz[a], c0.z, c0.w)));
                float d1 = fmaf(px[a], c1.x,
                             fmaf(py[a], c1.y, fmaf(pz[a], c1.z, c1.w)));
                rm[a] = fminf(fminf(rm[a], d0), d1);      // v_min3_f32
            }
        }
    }

    // fold over tc (lane bits 0..4)
#pragma unroll
    for (int a = 0; a < 8; ++a) {
        float v = rm[a];
        v = fminf(v, __shfl_xor(v, 1, 64));
        v = fminf(v, __shfl_xor(v, 2, 64));
        v = fminf(v, __shfl_xor(v, 4, 64));
        v = fminf(v, __shfl_xor(v, 8, 64));
        v = fminf(v, __shfl_xor(v, 16, 64));
        rm[a] = v;
    }
    if (tc == 0) {                           // lanes 0 & 32 of each wave
#pragma unroll
        for (int a = 0; a < 8; ++a) smin[a * 8 + tr] = rm[a];
    }
    __syncthreads();                         // full-semantics combine barrier
    if (tid < 64) {
        int row = rowbase + tid;             // matches smin[tid] mapping
        float v  = smin[tid];
        if (row < na) {
            float ps = A[row].w;             // |p|^2 (L1-hot reload)
            float vr = fmaxf(v + ps, 0.0f);  // nonneg -> int order ok
            atomicMin((int*)&rmG[(s << 14) + row], __float_as_int(vr));
        }
    }
}

// ---------------------------------------------------------------------------
// Kernel 3: sum the per-row mins (valid rows only) into out (proven R1).
// ---------------------------------------------------------------------------
__global__ __launch_bounds__(256) void finish_kernel(
        const int*   __restrict__ cnt,
        const float* __restrict__ rmG,
        float*       __restrict__ out) {
    int gid = blockIdx.x * 256 + threadIdx.x;    // 256 blocks x 256
    int s   = gid >> 14;
    int row = gid & (N_PTS - 1);
    int np0 = cnt[0], np1 = cnt[1], ng0 = cnt[2], ng1 = cnt[3];
    int naArr[4] = {np0, ng0, np1, ng1};
    int nbArr[4] = {ng0, np0, ng1, np1};
    float v = (row < naArr[s] && nbArr[s] > 0) ? rmG[gid] : 0.0f;
#pragma unroll
    for (int off = 32; off > 0; off >>= 1)
        v += __shfl_down(v, off, 64);
    __shared__ float wsum[4];
    if ((threadIdx.x & 63) == 0) wsum[threadIdx.x >> 6] = v;
    __syncthreads();
    if (threadIdx.x == 0) {
        float t = (wsum[0] + wsum[1]) + (wsum[2] + wsum[3]);
        atomicAdd(out, t * (1.0f / B_ITEMS));
    }
}

extern "C" void kernel_launch(void* const* d_in, const int* in_sizes, int n_in,
                              void* d_out, int out_size, void* d_ws, size_t ws_size,
                              hipStream_t stream) {
    const float* pred = (const float*)d_in[0];
    const float* gt   = (const float*)d_in[1];
    const int*   mask = (const int*)  d_in[2];
    const float* fx   = (const float*)d_in[3];
    const float* fy   = (const float*)d_in[4];
    const float* cx   = (const float*)d_in[5];
    const float* cy   = (const float*)d_in[6];
    float* out = (float*)d_out;

    // ws: [0,256) cnt | pR 512K | gR 512K | pT 512K | gT 512K | rmG 256K
    char* ws = (char*)d_ws;
    size_t SEG = (size_t)B_ITEMS * N_PTS * 16;
    int*    cnt = (int*)ws;
    float4* pR  = (float4*)(ws + 256);
    float4* gR  = (float4*)(ws + 256 + SEG);
    float4* pT  = (float4*)(ws + 256 + 2 * SEG);
    float4* gT  = (float4*)(ws + 256 + 3 * SEG);
    float*  rmG = (float*) (ws + 256 + 4 * SEG);

    hipMemsetAsync(cnt, 0, 16, stream);

    prep_kernel<<<dim3(256), 256, 0, stream>>>(
        pred, gt, mask, fx, fy, cx, cy, cnt, pR, gR, pT, gT, rmG, out);

    pad_kernel<<<dim3(4), 1024, 0, stream>>>(cnt, pT, gT);

    chamfer_kernel<<<dim3(CH_GRID), 256, 0, stream>>>(
        cnt, pR, gR, pT, gT, rmG);

    finish_kernel<<<dim3(256), 256, 0, stream>>>(cnt, rmG, out);
}